// Round 14
// baseline (272.406 us; speedup 1.0000x reference)
//
#include <hip/hip_runtime.h>
#include <math.h>

#define N_NODES 40000
#define N_EDGES 640000
#define IN_DIM 128
#define EDGE_DIM 64
#define HID 128

typedef __attribute__((ext_vector_type(8))) short bf16x8;
typedef __attribute__((ext_vector_type(4))) float f32x4;

__device__ __forceinline__ ushort f2bf(float f) {
    unsigned int x = __float_as_uint(f);
    x += 0x7fffu + ((x >> 16) & 1u);
    return (ushort)(x >> 16);
}
__device__ __forceinline__ float bf2f(ushort u) {
    return __uint_as_float(((unsigned int)u) << 16);
}
// tanh(x) = 1 - 2/(e^{2x}+1); e^{2x}=inf -> 1, e^{2x}=0 -> -1 (no NaN)
__device__ __forceinline__ float tanh_fast(float x) {
    return 1.f - __fdividef(2.f, __expf(2.f * x) + 1.f);
}

// ---------------------------------------------------------------------------
// Setup A: W_comb = W_edge @ W1[256:384]; b_eff = b_att1 + b_edge @ W1he
// ---------------------------------------------------------------------------
__global__ __launch_bounds__(256) void k_wcomb(
    const float* __restrict__ W_edge, const float* __restrict__ W1,
    const float* __restrict__ b_att1, const float* __restrict__ b_edge,
    float* __restrict__ Wc, float* __restrict__ b_eff)
{
    const float* W1he = W1 + 256 * 128;
    if (blockIdx.x == 32) {
        const int n = threadIdx.x;
        if (n < 128) {
            float s = b_att1[n];
            for (int k = 0; k < 128; ++k) s = fmaf(b_edge[k], W1he[k * 128 + n], s);
            b_eff[n] = s;
        }
        return;
    }
    const int idx = blockIdx.x * 256 + threadIdx.x;
    const int row = idx >> 7, n = idx & 127;
    float s = 0.f;
    for (int k = 0; k < 128; ++k) s = fmaf(W_edge[row * 128 + k], W1he[k * 128 + n], s);
    Wc[idx] = s;
}

// ---------------------------------------------------------------------------
// Setup B: pack all weight fragments, bf16.
//  idx<32768          : packB  (B-op, W1 rows 0..255, G1/G2 GEMMs)
//  32768..40959       : packA  (A-op, Wc^T, edge GEMM)
//  40960..57343       : packN  (B-op, W_node)
//  57344..73727       : packO  (B-op, W_out)
// ---------------------------------------------------------------------------
__global__ __launch_bounds__(256) void k_pack(
    const float* __restrict__ W1, const float* __restrict__ Wc,
    const float* __restrict__ Wn, const float* __restrict__ Wo,
    ushort* __restrict__ packB, ushort* __restrict__ packA,
    ushort* __restrict__ packN, ushort* __restrict__ packO)
{
    const int idx = blockIdx.x * 256 + threadIdx.x;   // 0..73727
    if (idx < 32768) {
        const int j = idx & 7, lane = (idx >> 3) & 63, nt = (idx >> 9) & 7, k0 = idx >> 12;
        const int k = k0 * 32 + (lane >> 4) * 8 + j;
        const int n = nt * 16 + (lane & 15);
        packB[idx] = f2bf(W1[k * 128 + n]);
    } else if (idx < 40960) {
        const int i2 = idx - 32768;
        const int j = i2 & 7, lane = (i2 >> 3) & 63, mt = (i2 >> 9) & 7, k0 = i2 >> 12;
        const int k = k0 * 32 + (lane >> 4) * 8 + j;
        const int row = mt * 16 + (lane & 15);
        packA[i2] = f2bf(Wc[k * 128 + row]);
    } else if (idx < 57344) {
        const int i3 = idx - 40960;
        const int j = i3 & 7, lane = (i3 >> 3) & 63, nt = (i3 >> 9) & 7, k0 = i3 >> 12;
        const int k = k0 * 32 + (lane >> 4) * 8 + j;
        const int n = nt * 16 + (lane & 15);
        packN[i3] = f2bf(Wn[k * 128 + n]);
    } else {
        const int i4 = idx - 57344;
        const int j = i4 & 7, lane = (i4 >> 3) & 63, nt = (i4 >> 9) & 7, k0 = i4 >> 12;
        const int k = k0 * 32 + (lane >> 4) * 8 + j;
        const int n = nt * 16 + (lane & 15);
        packO[i4] = f2bf(Wo[k * 128 + n]);
    }
}

// ---------------------------------------------------------------------------
// K1: h = X @ W_node + b_node via MFMA (X fp32 -> bf16 on the fly); Hb bf16.
// ---------------------------------------------------------------------------
__global__ __launch_bounds__(256) void k_node_gemm(
    const float* __restrict__ X, const ushort* __restrict__ packN,
    const float* __restrict__ b, ushort* __restrict__ Hb)
{
    const int tid = threadIdx.x;
    const int wave = tid >> 6, lane = tid & 63;
    const int r = lane & 15, g = lane >> 4;
    const int nbase = blockIdx.x * 64 + wave * 16;
    const float* rowX = X + (size_t)(nbase + r) * 128 + g * 8;
    const bf16x8* Bp = reinterpret_cast<const bf16x8*>(packN);

    f32x4 acc[8];
#pragma unroll
    for (int nt = 0; nt < 8; ++nt) {
        const float bv = b[nt * 16 + r];
        acc[nt] = (f32x4){bv, bv, bv, bv};
    }
#pragma unroll
    for (int k0 = 0; k0 < 4; ++k0) {
        const float4 u0 = *reinterpret_cast<const float4*>(rowX + k0 * 32);
        const float4 u1 = *reinterpret_cast<const float4*>(rowX + k0 * 32 + 4);
        bf16x8 a;
        a[0] = (short)f2bf(u0.x); a[1] = (short)f2bf(u0.y);
        a[2] = (short)f2bf(u0.z); a[3] = (short)f2bf(u0.w);
        a[4] = (short)f2bf(u1.x); a[5] = (short)f2bf(u1.y);
        a[6] = (short)f2bf(u1.z); a[7] = (short)f2bf(u1.w);
#pragma unroll
        for (int nt = 0; nt < 8; ++nt)
            acc[nt] = __builtin_amdgcn_mfma_f32_16x16x32_bf16(
                a, Bp[(k0 * 8 + nt) * 64 + lane], acc[nt], 0, 0, 0);
    }
#pragma unroll
    for (int nt = 0; nt < 8; ++nt) {
#pragma unroll
        for (int q = 0; q < 4; ++q)
            Hb[(size_t)(nbase + g * 4 + q) * 128 + nt * 16 + r] = f2bf(acc[nt][q]);
    }
}

// ---------------------------------------------------------------------------
// K1b: G1 = Hb @ W1a + b_eff ; G2 = Hb @ W1b   (both [N,128] bf16)
// ---------------------------------------------------------------------------
__global__ __launch_bounds__(256) void k_node_g12(
    const ushort* __restrict__ Hb, const ushort* __restrict__ packB,
    const float* __restrict__ b_eff,
    ushort* __restrict__ G1, ushort* __restrict__ G2)
{
    const int tid = threadIdx.x;
    const int wave = tid >> 6, lane = tid & 63;
    const int r = lane & 15, g = lane >> 4;
    const int nbase = blockIdx.x * 64 + wave * 16;
    const ushort* rowA = Hb + (size_t)(nbase + r) * 128 + g * 8;
    const bf16x8* Bp = reinterpret_cast<const bf16x8*>(packB);

    f32x4 acc[8];
#pragma unroll
    for (int nt = 0; nt < 8; ++nt) acc[nt] = (f32x4){0.f, 0.f, 0.f, 0.f};
#pragma unroll
    for (int k0 = 0; k0 < 4; ++k0) {
        const bf16x8 a = *reinterpret_cast<const bf16x8*>(rowA + k0 * 32);
#pragma unroll
        for (int nt = 0; nt < 8; ++nt)
            acc[nt] = __builtin_amdgcn_mfma_f32_16x16x32_bf16(
                a, Bp[(k0 * 8 + nt) * 64 + lane], acc[nt], 0, 0, 0);
    }
#pragma unroll
    for (int nt = 0; nt < 8; ++nt) {
        const float bv = b_eff[nt * 16 + r];
#pragma unroll
        for (int q = 0; q < 4; ++q)
            G1[(size_t)(nbase + g * 4 + q) * 128 + nt * 16 + r] = f2bf(acc[nt][q] + bv);
    }

#pragma unroll
    for (int nt = 0; nt < 8; ++nt) acc[nt] = (f32x4){0.f, 0.f, 0.f, 0.f};
#pragma unroll
    for (int k0 = 0; k0 < 4; ++k0) {
        const bf16x8 a = *reinterpret_cast<const bf16x8*>(rowA + k0 * 32);
#pragma unroll
        for (int nt = 0; nt < 8; ++nt)
            acc[nt] = __builtin_amdgcn_mfma_f32_16x16x32_bf16(
                a, Bp[((k0 + 4) * 8 + nt) * 64 + lane], acc[nt], 0, 0, 0);
    }
#pragma unroll
    for (int nt = 0; nt < 8; ++nt) {
#pragma unroll
        for (int q = 0; q < 4; ++q)
            G2[(size_t)(nbase + g * 4 + q) * 128 + nt * 16 + r] = f2bf(acc[nt][q]);
    }
}

// ---------------------------------------------------------------------------
// K2 v5: z^T = Wc^T @ EF^T (MFMA, A-frags straight from global/L2; no LDS,
// no __syncthreads) + G1[src] + G2[dst]; tanh; dot W2; exp; fused CSR fill.
// Cursor atomic HOISTED to kernel start (pos is independent of p) so the
// round-trip overlaps the MFMA+tanh body. One int2 record per edge.
// ---------------------------------------------------------------------------
__global__ __launch_bounds__(256) void k_edge_att_v5(
    const int* __restrict__ srcI, const int* __restrict__ dstI,
    const float* __restrict__ EF,
    const ushort* __restrict__ G1, const ushort* __restrict__ G2,
    const ushort* __restrict__ packA,
    const float* __restrict__ W2, const float* __restrict__ b2,
    const int* __restrict__ rowptr, int* __restrict__ cursor,
    int2* __restrict__ csr)
{
    const int tid = threadIdx.x;
    const int wave = tid >> 6, lane = tid & 63;
    const int r = lane & 15, g = lane >> 4;
    const int ebase = blockIdx.x * 64 + wave * 16;
    const int e = ebase + r;
    const int si = srcI[e], di = dstI[e];

    // hoisted CSR position (independent of p) — overlaps with body
    int pos = 0;
    if (lane < 16) pos = rowptr[si] + atomicAdd(&cursor[si], 1);

    // hoisted gathers: G1[src], G2[dst] rows in accumulator layout
    const ushort* g1row = G1 + (size_t)si * 128 + g * 4;
    const ushort* g2row = G2 + (size_t)di * 128 + g * 4;
    ushort4 g1v[8], g2v[8];
#pragma unroll
    for (int mt = 0; mt < 8; ++mt) {
        g1v[mt] = *reinterpret_cast<const ushort4*>(g1row + mt * 16);
        g2v[mt] = *reinterpret_cast<const ushort4*>(g2row + mt * 16);
    }

    // B-frags: EF[e][32*k0 + 8g + j], fp32 -> bf16
    const float* rowE = EF + (size_t)e * 64 + g * 8;
    bf16x8 b0, b1;
    {
        const float4 u0 = *reinterpret_cast<const float4*>(rowE);
        const float4 u1 = *reinterpret_cast<const float4*>(rowE + 4);
        b0[0] = (short)f2bf(u0.x); b0[1] = (short)f2bf(u0.y);
        b0[2] = (short)f2bf(u0.z); b0[3] = (short)f2bf(u0.w);
        b0[4] = (short)f2bf(u1.x); b0[5] = (short)f2bf(u1.y);
        b0[6] = (short)f2bf(u1.z); b0[7] = (short)f2bf(u1.w);
        const float4 v0 = *reinterpret_cast<const float4*>(rowE + 32);
        const float4 v1 = *reinterpret_cast<const float4*>(rowE + 36);
        b1[0] = (short)f2bf(v0.x); b1[1] = (short)f2bf(v0.y);
        b1[2] = (short)f2bf(v0.z); b1[3] = (short)f2bf(v0.w);
        b1[4] = (short)f2bf(v1.x); b1[5] = (short)f2bf(v1.y);
        b1[6] = (short)f2bf(v1.z); b1[7] = (short)f2bf(v1.w);
    }

    const bf16x8* Ap = reinterpret_cast<const bf16x8*>(packA);  // 16 KB, L2-hot
    f32x4 acc[8];
#pragma unroll
    for (int mt = 0; mt < 8; ++mt) acc[mt] = (f32x4){0.f, 0.f, 0.f, 0.f};
#pragma unroll
    for (int mt = 0; mt < 8; ++mt)
        acc[mt] = __builtin_amdgcn_mfma_f32_16x16x32_bf16(
            Ap[(0 * 8 + mt) * 64 + lane], b0, acc[mt], 0, 0, 0);
#pragma unroll
    for (int mt = 0; mt < 8; ++mt)
        acc[mt] = __builtin_amdgcn_mfma_f32_16x16x32_bf16(
            Ap[(1 * 8 + mt) * 64 + lane], b1, acc[mt], 0, 0, 0);

    // z += G1 + G2 ; a = sum tanh(z)*W2
    float part = 0.f;
#pragma unroll
    for (int mt = 0; mt < 8; ++mt) {
        const float4 w2v = *reinterpret_cast<const float4*>(W2 + mt * 16 + g * 4);
        const float z0 = acc[mt][0] + bf2f(g1v[mt].x) + bf2f(g2v[mt].x);
        const float z1 = acc[mt][1] + bf2f(g1v[mt].y) + bf2f(g2v[mt].y);
        const float z2 = acc[mt][2] + bf2f(g1v[mt].z) + bf2f(g2v[mt].z);
        const float z3 = acc[mt][3] + bf2f(g1v[mt].w) + bf2f(g2v[mt].w);
        part = fmaf(tanh_fast(z0), w2v.x, part);
        part = fmaf(tanh_fast(z1), w2v.y, part);
        part = fmaf(tanh_fast(z2), w2v.z, part);
        part = fmaf(tanh_fast(z3), w2v.w, part);
    }
    part += __shfl_xor(part, 16, 64);
    part += __shfl_xor(part, 32, 64);
    if (lane < 16) {
        const float p = __expf(part + b2[0]);
        int2 rec;
        rec.x = di;
        rec.y = __float_as_int(p);
        csr[pos] = rec;
    }
}

// ---------------------------------------------------------------------------
// CSR build: histogram -> single-block scan (4 elems/thread)
// ---------------------------------------------------------------------------
__global__ __launch_bounds__(256) void k_hist(
    const int* __restrict__ srcI, int* __restrict__ cnt)
{
    const int e = blockIdx.x * 256 + threadIdx.x;
    atomicAdd(&cnt[srcI[e]], 1);
}

__global__ __launch_bounds__(1024) void k_scan(
    const int* __restrict__ cnt, int* __restrict__ rowptr)
{
    __shared__ int wsum[16];
    __shared__ int carry;
    const int tid = threadIdx.x, lane = tid & 63, wid = tid >> 6;
    if (tid == 0) { carry = 0; rowptr[0] = 0; }
    __syncthreads();
    for (int base = 0; base < N_NODES; base += 4096) {
        const int i = base + tid * 4;
        int4 c = {0, 0, 0, 0};
        if (i < N_NODES) c = *reinterpret_cast<const int4*>(cnt + i);
        const int tsum = c.x + c.y + c.z + c.w;
        int v = tsum;
#pragma unroll
        for (int d = 1; d < 64; d <<= 1) {
            const int t = __shfl_up(v, d, 64);
            if (lane >= d) v += t;
        }
        if (lane == 63) wsum[wid] = v;
        __syncthreads();
        if (wid == 0 && lane < 16) {
            int w = wsum[lane];
#pragma unroll
            for (int d = 1; d < 16; d <<= 1) {
                const int t = __shfl_up(w, d, 16);
                if ((lane & 15) >= d) w += t;
            }
            wsum[lane] = w;
        }
        __syncthreads();
        const int off = (wid == 0) ? 0 : wsum[wid - 1];
        const int excl = carry + off + v - tsum;
        if (i < N_NODES) {
            rowptr[i + 1] = excl + c.x;
            rowptr[i + 2] = excl + c.x + c.y;
            rowptr[i + 3] = excl + c.x + c.y + c.z;
            rowptr[i + 4] = excl + tsum;
        }
        const int total = wsum[15];
        __syncthreads();
        if (tid == 0) carry += total;
        __syncthreads();
    }
}

// ---------------------------------------------------------------------------
// K3: per-node gather-aggregate, wave-per-node; int2 CSR records; bf16 out.
// ---------------------------------------------------------------------------
__global__ __launch_bounds__(256) void k_agg(
    const int* __restrict__ rowptr, const int2* __restrict__ csr,
    const ushort* __restrict__ Hb, ushort* __restrict__ AGGb)
{
    const int tid = threadIdx.x;
    const int wave = tid >> 6, lane = tid & 63;
    const int slot = lane >> 5, tc = lane & 31;
    const int n = blockIdx.x * 4 + wave;
    const int beg = rowptr[n], end = rowptr[n + 1];

    float4 v = {0.f, 0.f, 0.f, 0.f};
    float sp = 0.f;
    for (int j = beg + slot; j < end; j += 2) {
        const int2 rec = csr[j];
        const float p = __int_as_float(rec.y);
        const int d = rec.x;
        const ushort4 hv = *reinterpret_cast<const ushort4*>(Hb + (size_t)d * 128 + tc * 4);
        v.x = fmaf(p, bf2f(hv.x), v.x);
        v.y = fmaf(p, bf2f(hv.y), v.y);
        v.z = fmaf(p, bf2f(hv.z), v.z);
        v.w = fmaf(p, bf2f(hv.w), v.w);
        sp += p;
    }
    v.x += __shfl_xor(v.x, 32, 64);
    v.y += __shfl_xor(v.y, 32, 64);
    v.z += __shfl_xor(v.z, 32, 64);
    v.w += __shfl_xor(v.w, 32, 64);
    sp  += __shfl_xor(sp, 32, 64);
    if (lane < 32) {
        const float inv = (end > beg) ? 1.f / sp : 0.f;
        ushort4 o;
        o.x = f2bf(v.x * inv); o.y = f2bf(v.y * inv);
        o.z = f2bf(v.z * inv); o.w = f2bf(v.w * inv);
        *reinterpret_cast<ushort4*>(AGGb + (size_t)n * 128 + lane * 4) = o;
    }
}

// ---------------------------------------------------------------------------
// K4: o = agg @ W_out + b_out (MFMA) ; LayerNorm ; ReLU
// ---------------------------------------------------------------------------
__global__ __launch_bounds__(256) void k_out_ln(
    const ushort* __restrict__ AGGb, const ushort* __restrict__ packO,
    const float* __restrict__ b, const float* __restrict__ gamma,
    const float* __restrict__ beta, float* __restrict__ OUT)
{
    const int tid = threadIdx.x;
    const int wave = tid >> 6, lane = tid & 63;
    const int r = lane & 15, g = lane >> 4;
    const int nbase = blockIdx.x * 64 + wave * 16;
    const ushort* rowA = AGGb + (size_t)(nbase + r) * 128 + g * 8;
    const bf16x8* Bp = reinterpret_cast<const bf16x8*>(packO);

    f32x4 acc[8];
#pragma unroll
    for (int nt = 0; nt < 8; ++nt) {
        const float bv = b[nt * 16 + r];
        acc[nt] = (f32x4){bv, bv, bv, bv};
    }
#pragma unroll
    for (int k0 = 0; k0 < 4; ++k0) {
        const bf16x8 a = *reinterpret_cast<const bf16x8*>(rowA + k0 * 32);
#pragma unroll
        for (int nt = 0; nt < 8; ++nt)
            acc[nt] = __builtin_amdgcn_mfma_f32_16x16x32_bf16(
                a, Bp[(k0 * 8 + nt) * 64 + lane], acc[nt], 0, 0, 0);
    }

    float s1[4] = {0.f, 0.f, 0.f, 0.f};
    float s2[4] = {0.f, 0.f, 0.f, 0.f};
#pragma unroll
    for (int nt = 0; nt < 8; ++nt) {
#pragma unroll
        for (int q = 0; q < 4; ++q) {
            const float z = acc[nt][q];
            s1[q] += z;
            s2[q] = fmaf(z, z, s2[q]);
        }
    }
#pragma unroll
    for (int m = 1; m <= 8; m <<= 1) {
#pragma unroll
        for (int q = 0; q < 4; ++q) {
            s1[q] += __shfl_xor(s1[q], m, 64);
            s2[q] += __shfl_xor(s2[q], m, 64);
        }
    }
    float mu[4], rr[4];
#pragma unroll
    for (int q = 0; q < 4; ++q) {
        mu[q] = s1[q] * (1.f / 128.f);
        const float var = s2[q] * (1.f / 128.f) - mu[q] * mu[q];
        rr[q] = rsqrtf(var + 1e-5f);
    }
#pragma unroll
    for (int nt = 0; nt < 8; ++nt) {
        const int col = nt * 16 + r;
        const float ga = gamma[col], be = beta[col];
#pragma unroll
        for (int q = 0; q < 4; ++q) {
            const float o = (acc[nt][q] - mu[q]) * rr[q] * ga + be;
            OUT[(size_t)(nbase + g * 4 + q) * 128 + col] = o > 0.f ? o : 0.f;
        }
    }
}

// ---------------------------------------------------------------------------
extern "C" void kernel_launch(void* const* d_in, const int* in_sizes, int n_in,
                              void* d_out, int out_size, void* d_ws, size_t ws_size,
                              hipStream_t stream)
{
    const float* node_features = (const float*)d_in[0];
    const int*   edge_index    = (const int*)d_in[1];
    const float* edge_features = (const float*)d_in[2];
    const float* W_node  = (const float*)d_in[3];
    const float* b_node  = (const float*)d_in[4];
    const float* W_edge  = (const float*)d_in[5];
    const float* b_edge  = (const float*)d_in[6];
    const float* W_att1  = (const float*)d_in[7];
    const float* b_att1  = (const float*)d_in[8];
    const float* W_att2  = (const float*)d_in[9];
    const float* b_att2  = (const float*)d_in[10];
    const float* W_out   = (const float*)d_in[11];
    const float* b_out   = (const float*)d_in[12];
    const float* ln_gamma = (const float*)d_in[13];
    const float* ln_beta  = (const float*)d_in[14];
    float* out = (float*)d_out;

    // workspace layout (byte offsets, 16B-aligned)
    char* ws = (char*)d_ws;
    ushort* hb      = (ushort*)(ws);                   // 10,240,000 B
    ushort* G1      = (ushort*)(ws + 10240000);        // 10,240,000 B
    ushort* G2      = (ushort*)(ws + 20480000);        // 10,240,000 B
    ushort* aggb    = (ushort*)(ws + 30720000);        // 10,240,000 B
    int2*   csr     = (int2*)(ws + 40960000);          //  5,120,000 B
    int*    rowptr  = (int*)(ws + 46080000);           //    160,004 B
    int*    cnt     = (int*)(ws + 46240016);           //    160,000 B
    int*    cursor  = (int*)(ws + 46400016);           //    160,000 B (contiguous after cnt)
    float*  Wc      = (float*)(ws + 46560016);         //     32,768 B
    float*  b_eff   = (float*)(ws + 46592784);         //        512 B
    ushort* packB   = (ushort*)(ws + 46593296);        //     65,536 B
    ushort* packA   = (ushort*)(ws + 46658832);        //     16,384 B
    ushort* packN   = (ushort*)(ws + 46675216);        //     32,768 B
    ushort* packO   = (ushort*)(ws + 46707984);        //     32,768 B

    const int* srcI = edge_index;
    const int* dstI = edge_index + N_EDGES;

    // zero histogram + fill cursors (contiguous)
    hipMemsetAsync(cnt, 0, 320000, stream);

    k_wcomb<<<33, 256, 0, stream>>>(W_edge, W_att1, b_att1, b_edge, Wc, b_eff);
    k_pack<<<288, 256, 0, stream>>>(W_att1, Wc, W_node, W_out,
                                    packB, packA, packN, packO);
    k_node_gemm<<<N_NODES / 64, 256, 0, stream>>>(node_features, packN, b_node, hb);
    k_node_g12<<<N_NODES / 64, 256, 0, stream>>>(hb, packB, b_eff, G1, G2);
    k_hist<<<N_EDGES / 256, 256, 0, stream>>>(srcI, cnt);
    k_scan<<<1, 1024, 0, stream>>>(cnt, rowptr);
    k_edge_att_v5<<<N_EDGES / 64, 256, 0, stream>>>(srcI, dstI, edge_features,
                                                    G1, G2, packA, W_att2, b_att2,
                                                    rowptr, cursor, csr);
    k_agg<<<N_NODES / 4, 256, 0, stream>>>(rowptr, csr, hb, aggb);
    k_out_ln<<<N_NODES / 64, 256, 0, stream>>>(aggb, packO, b_out, ln_gamma, ln_beta, out);
}